// Round 14
// baseline (199.094 us; speedup 1.0000x reference)
//
#include <hip/hip_runtime.h>
#include <hip/hip_cooperative_groups.h>
#include <math.h>

namespace cg = cooperative_groups;

#define NN 100000
#define NE 1600000
#define BKT 448            // nodes per bucket (9-bit local index)
#define NB 224             // buckets == grid blocks (<=256 CUs, co-resident)
#define EPB 7168           // edges per chunk: 224*7168 >= NE; last chunk 1536
#define STRIDE 8960        // slots/bucket, mult of 4; padded mean ~7840, +13 sigma
#define RT 1024

// Self-restoring allocation cursors: zeroed at module load; phase B re-zeroes
// after its single read, so every launch/replay starts from zero.
__device__ unsigned g_cursor[NB];

struct SA {                    // phase A only
    int h[NB], lb[NB];
    unsigned gaddr[NB], glim[NB];
    int wsum[16];
    uint2 sga[EPB];            // 57.3 KB
};
struct SP {                    // phases B..D (persists across grid.sync)
    unsigned srt[STRIDE];      // 35.8 KB — sorted source indices, LDS-resident
    int cnt[BKT], rk[BKT], sexA[BKT], vA[BKT];
    int wsum[7];
    float w0[64], w1[64], wb[64], w2[64];
};
union SMem { SA a; SP p; };    // 61 KB static

__global__ void __launch_bounds__(RT, 1) gcn_mega(
        const float2* __restrict__ x2, const int* __restrict__ ei,
        const float* __restrict__ W1, const float* __restrict__ b1,
        const float* __restrict__ W2, const float* __restrict__ b2,
        float* __restrict__ out,
        unsigned* __restrict__ packed, float2* __restrict__ y2,
        float* __restrict__ z2)
{
    cg::grid_group grid = cg::this_grid();
    __shared__ SMem sm;
    const int t = threadIdx.x;
    const int lane = t & 63, wid = t >> 6;
    const int blk = blockIdx.x;
    const int* row = ei;
    const int* col = ei + NE;

    // ================= phase A: reorder into fixed-stride bucket runs =======
    {
        for (int i = t; i < NB; i += RT) sm.a.h[i] = 0;
        __syncthreads();

        const int e0 = blk * EPB;
        const int n = min(EPB, NE - e0);        // multiple of 4 (last = 1536)
        const int n4 = n >> 2;
        const int4* rv = (const int4*)(row + e0);
        const int4* cv = (const int4*)(col + e0);
        unsigned pk[8]; int bb[8];
#pragma unroll
        for (int u = 0; u < 8; ++u) bb[u] = -1;
#pragma unroll
        for (int g = 0; g < 2; ++g) {
            int grp = g * RT + t;
            if (grp < n4) {
                int4 r4 = rv[grp], c4 = cv[grp];
                int rr[4] = {r4.x, r4.y, r4.z, r4.w};
                int cc[4] = {c4.x, c4.y, c4.z, c4.w};
#pragma unroll
                for (int j = 0; j < 4; ++j) {
                    int b = cc[j] / BKT;        // compiler magic-mul
                    int cl = cc[j] - b * BKT;
                    pk[4 * g + j] = ((unsigned)rr[j] << 9) | (unsigned)cl;
                    bb[4 * g + j] = b;
                }
            }
        }
#pragma unroll
        for (int u = 0; u < 8; ++u)
            if (bb[u] >= 0) atomicAdd(&sm.a.h[bb[u]], 1);
        __syncthreads();

        // exclusive scan over NB bins (first 4 waves hold bins), wave-shfl
        int v = (t < NB) ? sm.a.h[t] : 0;
        int incl = v;
#pragma unroll
        for (int d = 1; d < 64; d <<= 1) {
            int u2 = __shfl_up(incl, d);
            if (lane >= d) incl += u2;
        }
        if (lane == 63) sm.a.wsum[wid] = incl;
        __syncthreads();
        int off = 0;
#pragma unroll
        for (int j = 0; j < 3; ++j)
            if (j < wid) off += sm.a.wsum[j];
        if (t < NB) {
            sm.a.lb[t] = off + incl - v;
            unsigned base = v ? atomicAdd(&g_cursor[t], (unsigned)v) : 0u;
            sm.a.gaddr[t] = (unsigned)t * STRIDE + base;
            sm.a.glim[t]  = (unsigned)(t + 1) * STRIDE;
        }
        __syncthreads();
        for (int i = t; i < NB; i += RT) sm.a.h[i] = 0;   // rank counters
        __syncthreads();

#pragma unroll
        for (int u = 0; u < 8; ++u) {
            if (bb[u] >= 0) {
                int b = bb[u];
                int r = atomicAdd(&sm.a.h[b], 1);
                unsigned a = sm.a.gaddr[b] + (unsigned)r;
                if (a >= sm.a.glim[b]) a = 0xFFFFFFFFu;   // never, statistically
                sm.a.sga[sm.a.lb[b] + r] = make_uint2(pk[u], a);
            }
        }
        __syncthreads();
        for (int i = t; i < n; i += RT) {
            uint2 e = sm.a.sga[i];
            if (e.y != 0xFFFFFFFFu) packed[e.y] = e.x;
        }
    }
    grid.sync();

    // ================= phase B: per-bucket counting sort (LDS-resident) =====
    const int b = blk;
    const int s0 = b * STRIDE;
    {
        const int L = min((int)g_cursor[b], STRIDE);
        const int L4 = L >> 2;
        for (int i = t; i < BKT; i += RT) { sm.p.cnt[i] = 0; sm.p.rk[i] = 0; }
        if (t >= 512 && t < 576) {              // stage weights once
            int j = t - 512;
            sm.p.w0[j] = W1[j]; sm.p.w1[j] = W1[64 + j];
            sm.p.wb[j] = b1[j]; sm.p.w2[j] = W2[j];
        }
        __syncthreads();
        if (t == 0) g_cursor[b] = 0u;           // restore invariant

        const uint4* pv4 = (const uint4*)(packed + s0);
        for (int g = t; g < L4; g += RT) {
            uint4 p4 = pv4[g];
            atomicAdd(&sm.p.cnt[p4.x & 511u], 1);
            atomicAdd(&sm.p.cnt[p4.y & 511u], 1);
            atomicAdd(&sm.p.cnt[p4.z & 511u], 1);
            atomicAdd(&sm.p.cnt[p4.w & 511u], 1);
        }
        for (int i = 4 * L4 + t; i < L; i += RT)
            atomicAdd(&sm.p.cnt[packed[s0 + i] & 511u], 1);
        __syncthreads();

        // padded (mult-of-4) exclusive scan over BKT bins -> 16B-aligned runs
        int v = (t < BKT) ? sm.p.cnt[t] : 0;
        int vp = (v + 3) & ~3;
        int incl = vp;
#pragma unroll
        for (int d = 1; d < 64; d <<= 1) {
            int u2 = __shfl_up(incl, d);
            if (lane >= d) incl += u2;
        }
        if (lane == 63 && wid < 7) sm.p.wsum[wid] = incl;
        __syncthreads();
        int off = 0;
#pragma unroll
        for (int j = 0; j < 6; ++j)
            if (j < wid) off += sm.p.wsum[j];
        if (t < BKT) {
            int sex = off + incl - vp;
            if (sex + v > STRIDE) v = max(0, STRIDE - sex);   // never
            sm.p.sexA[t] = sex;
            sm.p.vA[t] = v;
            int node = b * BKT + t;
            if (node < NN) {
                float dv = (v > 0) ? rsqrtf((float)v) : 0.0f;
                float2 xv = x2[node];
                y2[node] = make_float2(xv.x * dv, xv.y * dv);
            }
        }
        __syncthreads();

        // rank-scatter into LDS srt (re-read L2-hot packed)
        for (int g = t; g < L4; g += RT) {
            uint4 p4 = pv4[g];
            unsigned pp[4] = {p4.x, p4.y, p4.z, p4.w};
#pragma unroll
            for (int j = 0; j < 4; ++j) {
                int cl = pp[j] & 511u;
                int r = atomicAdd(&sm.p.rk[cl], 1);
                int idx = sm.p.sexA[cl] + r;
                if (idx < STRIDE) sm.p.srt[idx] = pp[j] >> 9;
            }
        }
        for (int i = 4 * L4 + t; i < L; i += RT) {
            unsigned p = packed[s0 + i];
            int cl = p & 511u;
            int r = atomicAdd(&sm.p.rk[cl], 1);
            int idx = sm.p.sexA[cl] + r;
            if (idx < STRIDE) sm.p.srt[idx] = p >> 9;
        }
    }
    grid.sync();   // all y2 visible; srt stays in this block's LDS

    // ================= phase C: conv1 + fused MLP -> z2 =====================
    {
        const int qlane = t & 3;
        const int q = t >> 2;                   // 0..255
        for (int nd = q; nd < BKT; nd += RT / 4) {
            int node = b * BKT + nd;
            if (node >= NN) break;
            int v = sm.p.vA[nd];
            const uint4* s4 = (const uint4*)(sm.p.srt + sm.p.sexA[nd]);
            float sx = 0.f, sy = 0.f;
            for (int g = qlane; 4 * g < v; g += 4) {
                uint4 i4 = s4[g];
                unsigned ii[4] = {i4.x, i4.y, i4.z, i4.w};
#pragma unroll
                for (int j = 0; j < 4; ++j) {
                    if (4 * g + j < v) {
                        float2 vy = y2[ii[j]];
                        sx += vy.x; sy += vy.y;
                    }
                }
            }
            sx += __shfl_xor(sx, 1); sy += __shfl_xor(sy, 1);
            sx += __shfl_xor(sx, 2); sy += __shfl_xor(sy, 2);
            float dv = (v > 0) ? rsqrtf((float)v) : 0.0f;
            float a0 = sx * dv, a1 = sy * dv;
            float acc = 0.0f;
            const int j0 = qlane * 16;
#pragma unroll
            for (int jj = 0; jj < 16; ++jj) {
                int j = j0 + jj;
                float h = fmaf(a0, sm.p.w0[j], fmaf(a1, sm.p.w1[j], sm.p.wb[j]));
                acc = fmaf(fmaxf(h, 0.0f), sm.p.w2[j], acc);
            }
            acc += __shfl_xor(acc, 1);
            acc += __shfl_xor(acc, 2);
            if (qlane == 0) z2[node] = acc * dv;
        }
    }
    grid.sync();   // all z2 visible

    // ================= phase D: conv2 + bias + relu -> out ==================
    {
        const int qlane = t & 3;
        const int q = t >> 2;
        const float bias = b2[0];
        for (int nd = q; nd < BKT; nd += RT / 4) {
            int node = b * BKT + nd;
            if (node >= NN) break;
            int v = sm.p.vA[nd];
            const uint4* s4 = (const uint4*)(sm.p.srt + sm.p.sexA[nd]);
            float s = 0.f;
            for (int g = qlane; 4 * g < v; g += 4) {
                uint4 i4 = s4[g];
                unsigned ii[4] = {i4.x, i4.y, i4.z, i4.w};
#pragma unroll
                for (int j = 0; j < 4; ++j)
                    if (4 * g + j < v) s += z2[ii[j]];
            }
            s += __shfl_xor(s, 1);
            s += __shfl_xor(s, 2);
            if (qlane == 0) {
                float dv = (v > 0) ? rsqrtf((float)v) : 0.0f;
                out[node] = fmaxf(fmaf(dv, s, bias), 0.0f);
            }
        }
    }
}

// ---------- launch ----------
extern "C" void kernel_launch(void* const* d_in, const int* in_sizes, int n_in,
                              void* d_out, int out_size, void* d_ws, size_t ws_size,
                              hipStream_t stream) {
    const float2* x2 = (const float2*)d_in[0];
    const int*    ei = (const int*)d_in[1];    // [2, E] int32: row then col
    const float*  W1 = (const float*)d_in[2];
    const float*  b1 = (const float*)d_in[3];
    const float*  W2 = (const float*)d_in[4];
    const float*  b2 = (const float*)d_in[5];
    float* out = (float*)d_out;

    unsigned* packed = (unsigned*)d_ws;                         // NB*STRIDE (~8 MB)
    float2*   y2     = (float2*)(packed + (size_t)NB * STRIDE); // NN float2
    float*    z2     = (float*)(y2 + NN);                       // NN

    void* args[] = {
        (void*)&x2, (void*)&ei, (void*)&W1, (void*)&b1, (void*)&W2, (void*)&b2,
        (void*)&out, (void*)&packed, (void*)&y2, (void*)&z2
    };
    hipLaunchCooperativeKernel((const void*)gcn_mega, dim3(NB), dim3(RT),
                               args, 0, stream);
}

// Round 15
// 112.410 us; speedup vs baseline: 1.7711x; 1.7711x over previous
//
#include <hip/hip_runtime.h>
#include <math.h>

#define NN 100000
#define NE 1600000
#define BKT 448            // nodes per bucket (non-pow2; 9-bit local index)
#define NB 224             // ceil(100000/448) -> single round on 256 CUs
#define EPB 6400           // edges per reorder chunk; 250*6400 = 1,600,000 exact
#define NPB 250            // reorder grid -> single round on 256 CUs
#define STRIDE 8192        // slots per bucket (mean 7168, sd ~85 -> +12 sigma)
#define RT 1024

// Self-restoring allocation cursors: zero-initialized at module load; sortb
// re-zeroes each bucket's entry after its single read, so every call (and
// every graph replay) starts from zero without a memset dispatch.
__device__ unsigned g_cursor[NB];

// ---------- K1: reorder edges into fixed-stride bucket runs ----------
// packed record = (row << 9) | cl, cl = col - bucket*448 (< 448 < 512)
__global__ void __launch_bounds__(RT) reorder_kernel(
        const int* __restrict__ row, const int* __restrict__ col,
        unsigned* __restrict__ packed) {
    __shared__ int h[NB], lb[NB];
    __shared__ unsigned gaddr[NB], glim[NB];
    __shared__ int wsum[RT / 64];
    __shared__ uint2 sga[EPB];                 // (record, final global slot) — 50 KB
    const int t = threadIdx.x;
    const int lane = t & 63, wid = t >> 6;
    const int e0 = blockIdx.x * EPB;

    for (int i = t; i < NB; i += RT) h[i] = 0;
    __syncthreads();

    // ---- load up to 2 int4 groups (1600 groups, 1024 threads) ----
    const int4* rv = (const int4*)(row + e0);
    const int4* cv = (const int4*)(col + e0);
    unsigned pk[8]; int bb[8];
#pragma unroll
    for (int u = 0; u < 8; ++u) bb[u] = -1;
#pragma unroll
    for (int g = 0; g < 2; ++g) {
        int grp = g * RT + t;
        if (grp < EPB / 4) {
            int4 r4 = rv[grp], c4 = cv[grp];
            int rr[4] = {r4.x, r4.y, r4.z, r4.w};
            int cc[4] = {c4.x, c4.y, c4.z, c4.w};
#pragma unroll
            for (int j = 0; j < 4; ++j) {
                int b = cc[j] / BKT;            // compiler magic-mul
                int cl = cc[j] - b * BKT;
                pk[4 * g + j] = ((unsigned)rr[j] << 9) | (unsigned)cl;
                bb[4 * g + j] = b;
            }
        }
    }
#pragma unroll
    for (int u = 0; u < 8; ++u)
        if (bb[u] >= 0) atomicAdd(&h[bb[u]], 1);
    __syncthreads();

    // ---- exclusive scan over NB bins, wave-shfl ----
    int v = (t < NB) ? h[t] : 0;
    int incl = v;
#pragma unroll
    for (int d = 1; d < 64; d <<= 1) {
        int u2 = __shfl_up(incl, d);
        if (lane >= d) incl += u2;
    }
    if (lane == 63) wsum[wid] = incl;
    __syncthreads();
    int off = 0;
#pragma unroll
    for (int j = 0; j < 3; ++j)                // NB=224 -> 4 waves cover the bins
        if (j < wid) off += wsum[j];
    if (t < NB) {
        lb[t] = off + incl - v;
        unsigned base = v ? atomicAdd(&g_cursor[t], (unsigned)v) : 0u;
        gaddr[t] = (unsigned)t * STRIDE + base;
        glim[t]  = (unsigned)(t + 1) * STRIDE;
    }
    __syncthreads();
    for (int i = t; i < NB; i += RT) h[i] = 0;  // reuse as rank counters
    __syncthreads();

    // ---- rank-scatter into LDS with precomputed final address ----
#pragma unroll
    for (int u = 0; u < 8; ++u) {
        if (bb[u] >= 0) {
            int b = bb[u];
            int r = atomicAdd(&h[b], 1);
            unsigned a = gaddr[b] + (unsigned)r;
            if (a >= glim[b]) a = 0xFFFFFFFFu;  // overflow guard (statistically never)
            sga[lb[b] + r] = make_uint2(pk[u], a);
        }
    }
    __syncthreads();
    // ---- write-out: one ds_read_b64 + store per edge, run-coalesced ----
    for (int i = t; i < EPB; i += RT) {
        uint2 e = sga[i];
        if (e.y != 0xFFFFFFFFu) packed[e.y] = e.x;
    }
}

// ---------- K2: per-bucket counting sort -> CSR runs + dis + y2 ----------
__global__ void __launch_bounds__(RT) sortb_kernel(
        const unsigned* __restrict__ packed, const float2* __restrict__ x2,
        unsigned* __restrict__ srow, int2* __restrict__ node_rng,
        float* __restrict__ dis, float2* __restrict__ y2) {
    __shared__ int cnt[BKT], rk[BKT], sexA[BKT];
    __shared__ int wsum[(BKT + 63) / 64];      // 7
    __shared__ unsigned srt[STRIDE];           // 32 KB
    const int t = threadIdx.x;
    const int lane = t & 63, wid = t >> 6;
    const int b = blockIdx.x;
    const unsigned s0 = (unsigned)b * STRIDE;
    const int L = min((int)g_cursor[b], STRIDE);
    const int L4 = L >> 2;

    for (int i = t; i < BKT; i += RT) { cnt[i] = 0; rk[i] = 0; }
    __syncthreads();
    if (t == 0) g_cursor[b] = 0u;              // restore invariant for next call

    // ---- pass 1: histogram (uint4 global reads; no LDS staging) ----
    const uint4* pv4 = (const uint4*)(packed + s0);
    for (int g = t; g < L4; g += RT) {
        uint4 p4 = pv4[g];
        atomicAdd(&cnt[p4.x & 511u], 1);
        atomicAdd(&cnt[p4.y & 511u], 1);
        atomicAdd(&cnt[p4.z & 511u], 1);
        atomicAdd(&cnt[p4.w & 511u], 1);
    }
    for (int i = 4 * L4 + t; i < L; i += RT)
        atomicAdd(&cnt[packed[s0 + i] & 511u], 1);
    __syncthreads();

    // ---- exclusive scan over BKT bins, wave-shfl (7 waves) ----
    int v = (t < BKT) ? cnt[t] : 0;
    int incl = v;
#pragma unroll
    for (int d = 1; d < 64; d <<= 1) {
        int u2 = __shfl_up(incl, d);
        if (lane >= d) incl += u2;
    }
    if (lane == 63 && wid < (BKT + 63) / 64) wsum[wid] = incl;
    __syncthreads();
    int off = 0;
#pragma unroll
    for (int j = 0; j < (BKT + 63) / 64 - 1; ++j)
        if (j < wid) off += wsum[j];
    if (t < BKT) {
        int sex = off + incl - v;
        sexA[t] = sex;
        int node = b * BKT + t;
        if (node < NN) {
            float dv = (v > 0) ? rsqrtf((float)v) : 0.0f;
            dis[node] = dv;
            float2 xv = x2[node];
            y2[node] = make_float2(xv.x * dv, xv.y * dv);
            node_rng[node] = make_int2((int)(s0 + sex), (int)(s0 + sex + v));
        }
    }
    __syncthreads();

    // ---- pass 2: rank-scatter (re-read L2-hot packed) ----
    for (int g = t; g < L4; g += RT) {
        uint4 p4 = pv4[g];
        unsigned pp[4] = {p4.x, p4.y, p4.z, p4.w};
#pragma unroll
        for (int j = 0; j < 4; ++j) {
            int cl = pp[j] & 511u;
            int r = atomicAdd(&rk[cl], 1);
            srt[sexA[cl] + r] = pp[j] >> 9;
        }
    }
    for (int i = 4 * L4 + t; i < L; i += RT) {
        unsigned p = packed[s0 + i];
        int cl = p & 511u;
        int r = atomicAdd(&rk[cl], 1);
        srt[sexA[cl] + r] = p >> 9;
    }
    __syncthreads();
    // ---- coalesced write-out (uint4) ----
    uint4* so4 = (uint4*)(srow + s0);
    for (int g = t; g < L4; g += RT) so4[g] = ((const uint4*)srt)[g];
    for (int i = 4 * L4 + t; i < L; i += RT) srow[s0 + i] = srt[i];
}

// ---------- K3: conv1 — 4-lane quad per node, CSR gather + fused MLP ----------
__global__ void conv1_kernel(const unsigned* __restrict__ srow, const int2* __restrict__ node_rng,
                             const float2* __restrict__ y2, const float* __restrict__ dis,
                             const float* __restrict__ W1, const float* __restrict__ b1,
                             const float* __restrict__ W2, float* __restrict__ z2) {
    __shared__ float sW0[64], sW1[64], sb1[64], sW2[64];
    int t = threadIdx.x;
    if (t < 64) { sW0[t] = W1[t]; sW1[t] = W1[64 + t]; sb1[t] = b1[t]; sW2[t] = W2[t]; }
    __syncthreads();
    int lane = t & 3;
    int node = blockIdx.x * 64 + (t >> 2);
    if (node >= NN) return;
    int2 rng = node_rng[node];
    float sx = 0.f, sy = 0.f;
    for (int k = rng.x + lane; k < rng.y; k += 4) {
        float2 v = y2[srow[k]];
        sx += v.x; sy += v.y;
    }
    sx += __shfl_xor(sx, 1); sy += __shfl_xor(sy, 1);
    sx += __shfl_xor(sx, 2); sy += __shfl_xor(sy, 2);
    float dv = dis[node];
    float a0 = sx * dv, a1 = sy * dv;
    float acc = 0.0f;
    int j0 = lane * 16;
#pragma unroll
    for (int jj = 0; jj < 16; ++jj) {
        int j = j0 + jj;
        float h = fmaf(a0, sW0[j], fmaf(a1, sW1[j], sb1[j]));
        acc = fmaf(fmaxf(h, 0.0f), sW2[j], acc);
    }
    acc += __shfl_xor(acc, 1);
    acc += __shfl_xor(acc, 2);
    if (lane == 0) z2[node] = acc * dv;
}

// ---------- K4: conv2 — 4-lane quad per node, CSR gather + bias + relu ----------
__global__ void conv2_kernel(const unsigned* __restrict__ srow, const int2* __restrict__ node_rng,
                             const float* __restrict__ z2, const float* __restrict__ dis,
                             const float* __restrict__ b2, float* __restrict__ out) {
    int t = threadIdx.x;
    int lane = t & 3;
    int node = blockIdx.x * 64 + (t >> 2);
    if (node >= NN) return;
    int2 rng = node_rng[node];
    float s = 0.f;
    for (int k = rng.x + lane; k < rng.y; k += 4)
        s += z2[srow[k]];
    s += __shfl_xor(s, 1);
    s += __shfl_xor(s, 2);
    if (lane == 0)
        out[node] = fmaxf(fmaf(dis[node], s, b2[0]), 0.0f);
}

// ---------- launch ----------
extern "C" void kernel_launch(void* const* d_in, const int* in_sizes, int n_in,
                              void* d_out, int out_size, void* d_ws, size_t ws_size,
                              hipStream_t stream) {
    const float* x  = (const float*)d_in[0];
    const int*   ei = (const int*)d_in[1];     // [2, E] int32: row then col
    const float* W1 = (const float*)d_in[2];
    const float* b1 = (const float*)d_in[3];
    const float* W2 = (const float*)d_in[4];
    const float* b2 = (const float*)d_in[5];
    float* out = (float*)d_out;

    const int* row = ei;
    const int* col = ei + NE;

    // workspace layout
    unsigned* packed   = (unsigned*)d_ws;              // NB*STRIDE (~7.3 MB)
    unsigned* srow     = packed + (size_t)NB * STRIDE; // NB*STRIDE (~7.3 MB)
    float2*   y2       = (float2*)(srow + (size_t)NB * STRIDE); // NN float2
    float*    dis      = (float*)(y2 + NN);            // NN
    float*    z2       = dis + NN;                     // NN
    int2*     node_rng = (int2*)(z2 + NN);             // NN int2

    reorder_kernel<<<NPB, RT, 0, stream>>>(row, col, packed);
    sortb_kernel  <<<NB, RT, 0, stream>>>(packed, (const float2*)x,
                                          srow, node_rng, dis, y2);
    conv1_kernel  <<<(NN + 63) / 64, 256, 0, stream>>>(srow, node_rng, y2, dis,
                                                       W1, b1, W2, z2);
    conv2_kernel  <<<(NN + 63) / 64, 256, 0, stream>>>(srow, node_rng, z2, dis, b2, out);
}